// Round 3
// baseline (556.730 us; speedup 1.0000x reference)
//
#include <hip/hip_runtime.h>
#include <hip/hip_bf16.h>
#include <stdint.h>

// JinaEmbeddingsV3SelfOutput, algebraically folded:
//   h2 = hs @ Weff_t^T + beff_t,   Weff_t = W@W + 0.25*B_t@(A_t@W)  [per task]
//   beff_t = W@b + b + 0.25*B_t@(A_t@b)
//   out = LN(h2 + input)
// R3: gemm_main rebuilt as counted-vmcnt 3-buffer pipeline (T3/T4 minimum);
//     A2 folded into the Wc GEMM as extra M-rows ([W;lA]@W) killing the
//     5120-block a2c role; dead LDS XOR swizzle removed (bank counter proved
//     b128's 8-lane/group is already optimal).
#define D_HID 1024
#define M_TOT 32768
#define LN_EPS 1e-5f

typedef __bf16 bf16x8 __attribute__((ext_vector_type(8)));
typedef float f32x4 __attribute__((ext_vector_type(4)));
typedef unsigned short u16;
typedef u16 u16x8 __attribute__((ext_vector_type(8)));
typedef u16 u16x4v __attribute__((ext_vector_type(4)));

__device__ __forceinline__ float bf2f(u16 x) {
  union { unsigned int u; float f; } c; c.u = ((unsigned int)x) << 16; return c.f;
}
__device__ __forceinline__ u16 f2bf(float f) {
  union { __bf16 h; u16 u; } c; c.h = (__bf16)f; return c.u;  // RNE
}
__device__ __forceinline__ u16x8 cvt8(const float* g) {
  float4 f0 = *(const float4*)g;
  float4 f1 = *(const float4*)(g + 4);
  u16x8 v;
  v[0] = f2bf(f0.x); v[1] = f2bf(f0.y); v[2] = f2bf(f0.z); v[3] = f2bf(f0.w);
  v[4] = f2bf(f1.x); v[5] = f2bf(f1.y); v[6] = f2bf(f1.z); v[7] = f2bf(f1.w);
  return v;
}
// Async global->LDS, 16B/lane. LDS dest is wave-uniform base + lane*16.
__device__ __forceinline__ void gld16(const u16* g, u16* lds_wave_base) {
  __builtin_amdgcn_global_load_lds(
      (__attribute__((address_space(1))) unsigned int*)g,
      (__attribute__((address_space(3))) unsigned int*)lds_wave_base, 16, 0, 0);
}

// ---- S1: hs->bf16 (blocks 0..2047), W split+transpose (2048..3071),
//          lA zero-padded split (3072..3079) ----
__global__ __launch_bounds__(256) void s1_prep(
    const float* __restrict__ hs, u16* __restrict__ hs_bf,
    const float* __restrict__ W, u16* __restrict__ hi, u16* __restrict__ lo,
    u16* __restrict__ hiT, u16* __restrict__ loT,
    const float* __restrict__ lA, u16* __restrict__ lAh, u16* __restrict__ lAl) {
  __shared__ float tile[32][33];
  const int bid = blockIdx.x, tid = threadIdx.x;
  if (bid < 2048) {
    int i = bid * 256 + tid;          // 2048*256*8 == 32768*1024/8 exactly
#pragma unroll
    for (int it = 0; it < 8; ++it, i += 2048 * 256)
      *(u16x8*)(hs_bf + (size_t)i * 8) = cvt8(hs + (size_t)i * 8);
    return;
  }
  if (bid >= 3072) {                  // lA pad+split: 128x1024, rows >=20 zero
    const int b = bid - 3072;         // 0..7, rows b*16..b*16+15
    for (int i = tid; i < 16 * 1024; i += 256) {
      const int r = b * 16 + (i >> 10), c = i & 1023;
      const float v = (r < 20) ? lA[(size_t)r * 1024 + c] : 0.f;
      const u16 h = f2bf(v);
      lAh[(size_t)r * 1024 + c] = h;
      lAl[(size_t)r * 1024 + c] = f2bf(v - bf2f(h));
    }
    return;
  }
  const int rb = bid - 2048;
  const int bj = rb & 31, bi = rb >> 5;
  const int tx = tid & 31, ty = tid >> 5;
#pragma unroll
  for (int r0 = 0; r0 < 32; r0 += 8) {
    const int r = r0 + ty;
    const size_t o = (size_t)(bi * 32 + r) * D_HID + bj * 32 + tx;
    const float v = W[o];
    tile[r][tx] = v;
    const u16 h = f2bf(v);
    hi[o] = h; lo[o] = f2bf(v - bf2f(h));
  }
  __syncthreads();
#pragma unroll
  for (int r0 = 0; r0 < 32; r0 += 8) {
    const int r = r0 + ty;
    const float v = tile[tx][r];  // WT[bj*32+r][bi*32+tx]
    const size_t o = (size_t)(bj * 32 + r) * D_HID + bi * 32 + tx;
    const u16 h = f2bf(v);
    hiT[o] = h; loT[o] = f2bf(v - bf2f(h));
  }
}

// ---- S2: [W; lApad] @ W via split-bf16 MFMA. by<8 -> Wc tile; by==8 -> A2
//      rows (only first 20 kept). 72 blocks total. ----
__global__ __launch_bounds__(256, 1) void s2_gemm(
    const u16* __restrict__ Ah, const u16* __restrict__ Al,
    const u16* __restrict__ Bh, const u16* __restrict__ Bl,
    const u16* __restrict__ lAh, const u16* __restrict__ lAl,
    float* __restrict__ C, float* __restrict__ A2) {
  __shared__ __align__(16) u16 sAh[128 * 32], sAl[128 * 32];
  __shared__ __align__(16) u16 sBh[128 * 32], sBl[128 * 32];
  const int bid = blockIdx.x, tid = threadIdx.x, wave = tid >> 6, lane = tid & 63;
  const int by = bid >> 3, bx = bid & 7;
  const bool isA2 = (by == 8);
  const u16* Asrc_h = isA2 ? lAh : Ah;
  const u16* Asrc_l = isA2 ? lAl : Al;
  const int rowbase = isA2 ? 0 : by * 128;
  const int srow = tid >> 2, scol = (tid & 3) * 8;
  size_t aOff = (size_t)(rowbase + srow) * D_HID + scol;
  size_t bOff = (size_t)(bx * 128 + srow) * D_HID + scol;
  const int wb = wave * 512;
  const int wm = wave >> 1, wn = wave & 1;
  const int mrow = lane & 15, quad = lane >> 4;
  const int fA = (wm * 64 + mrow) * 32 + quad * 8;
  const int fB = (wn * 64 + mrow) * 32 + quad * 8;
  f32x4 acc[4][4];
#pragma unroll
  for (int i = 0; i < 4; ++i)
#pragma unroll
    for (int j = 0; j < 4; ++j) acc[i][j] = (f32x4){0.f, 0.f, 0.f, 0.f};
  for (int k0 = 0; k0 < D_HID; k0 += 32) {
    __syncthreads();
    gld16(Asrc_h + aOff, sAh + wb); gld16(Asrc_h + aOff + 64 * D_HID, sAh + wb + 2048);
    gld16(Asrc_l + aOff, sAl + wb); gld16(Asrc_l + aOff + 64 * D_HID, sAl + wb + 2048);
    gld16(Bh + bOff, sBh + wb); gld16(Bh + bOff + 64 * D_HID, sBh + wb + 2048);
    gld16(Bl + bOff, sBl + wb); gld16(Bl + bOff + 64 * D_HID, sBl + wb + 2048);
    aOff += 32; bOff += 32;
    __syncthreads();
    bf16x8 ah[4], al4[4], bh[4], bl4[4];
#pragma unroll
    for (int m = 0; m < 4; ++m) {
      ah[m]  = *(const bf16x8*)(sAh + fA + m * 512);
      al4[m] = *(const bf16x8*)(sAl + fA + m * 512);
    }
#pragma unroll
    for (int n = 0; n < 4; ++n) {
      bh[n]  = *(const bf16x8*)(sBh + fB + n * 512);
      bl4[n] = *(const bf16x8*)(sBl + fB + n * 512);
    }
#pragma unroll
    for (int m = 0; m < 4; ++m)
#pragma unroll
      for (int n = 0; n < 4; ++n) {
        acc[m][n] = __builtin_amdgcn_mfma_f32_16x16x32_bf16(ah[m],  bh[n],  acc[m][n], 0, 0, 0);
        acc[m][n] = __builtin_amdgcn_mfma_f32_16x16x32_bf16(al4[m], bh[n],  acc[m][n], 0, 0, 0);
        acc[m][n] = __builtin_amdgcn_mfma_f32_16x16x32_bf16(ah[m],  bl4[n], acc[m][n], 0, 0, 0);
      }
  }
  const int nBase = bx * 128 + wn * 64;
#pragma unroll
  for (int m = 0; m < 4; ++m)
#pragma unroll
    for (int n = 0; n < 4; ++n) {
      const int nn = nBase + n * 16 + mrow;
#pragma unroll
      for (int r = 0; r < 4; ++r) {
        const int lr = wm * 64 + m * 16 + quad * 4 + r;  // local row in tile
        if (!isA2) {
          C[(size_t)(by * 128 + lr) * D_HID + nn] = acc[m][n][r];
        } else if (lr < 20) {
          A2[(size_t)lr * D_HID + nn] = acc[m][n][r];
        }
      }
    }
}

// ---- S3: Weff_t = bf16(Wc + 0.25*B_t@A2_t); beff_t (cvec dots inline) ----
__global__ __launch_bounds__(256) void weff_beff(
    const float* __restrict__ Wc, const float* __restrict__ A2,
    const float* __restrict__ lB, const float* __restrict__ lA,
    const float* __restrict__ W, const float* __restrict__ bvec,
    u16* __restrict__ Weff, float* __restrict__ beff) {
  const int n = blockIdx.x, t = blockIdx.y, tid = threadIdx.x;
  const int wave = tid >> 6, lane = tid & 63;
  float br[4];
#pragma unroll
  for (int r = 0; r < 4; ++r) br[r] = lB[(size_t)t * 4096 + n * 4 + r];
  float4 v = *(const float4*)(Wc + (size_t)n * D_HID + tid * 4);
#pragma unroll
  for (int r = 0; r < 4; ++r) {
    const float4 a2 = *(const float4*)(A2 + (size_t)(t * 4 + r) * D_HID + tid * 4);
    const float s = 0.25f * br[r];
    v.x += s * a2.x; v.y += s * a2.y; v.z += s * a2.z; v.w += s * a2.w;
  }
  u16x4v o; o[0] = f2bf(v.x); o[1] = f2bf(v.y); o[2] = f2bf(v.z); o[3] = f2bf(v.w);
  *(u16x4v*)(Weff + (size_t)t * 1048576 + (size_t)n * D_HID + tid * 4) = o;
  // beff[t][n] = W[n,:]·b + b[n] + 0.25 * sum_r B_t[n,r] * (lA[t,r,:]·b)
  const float4 bb = *(const float4*)(bvec + tid * 4);
  float p[5];
  {
    const float4 wr = *(const float4*)(W + (size_t)n * D_HID + tid * 4);
    p[0] = wr.x * bb.x + wr.y * bb.y + wr.z * bb.z + wr.w * bb.w;
  }
#pragma unroll
  for (int r = 0; r < 4; ++r) {
    const float4 ar = *(const float4*)(lA + (size_t)(t * 4 + r) * D_HID + tid * 4);
    p[1 + r] = ar.x * bb.x + ar.y * bb.y + ar.z * bb.z + ar.w * bb.w;
  }
#pragma unroll
  for (int m = 1; m < 64; m <<= 1)
#pragma unroll
    for (int j = 0; j < 5; ++j) p[j] += __shfl_xor(p[j], m);
  __shared__ float red[4][5];
  if (lane == 0)
#pragma unroll
    for (int j = 0; j < 5; ++j) red[wave][j] = p[j];
  __syncthreads();
  if (tid == 0) {
    float P = 0.f, Cr[4] = {0.f, 0.f, 0.f, 0.f};
#pragma unroll
    for (int w = 0; w < 4; ++w) {
      P += red[w][0];
#pragma unroll
      for (int r = 0; r < 4; ++r) Cr[r] += red[w][1 + r];
    }
    float e = 0.f;
#pragma unroll
    for (int r = 0; r < 4; ++r) e += br[r] * Cr[r];
    beff[t * D_HID + n] = P + bvec[n] + 0.25f * e;
  }
}

// ---- main GEMM: out = hs_bf @ Weff[task]^T + beff + resid ----
// Counted-vmcnt 3-buffer pipeline, stage 2 tiles ahead, never drain to 0 in
// the main loop. Hazard argument:
//  * tile-t data ready: each wave waits vmcnt(<=2*4 newer) => its own 4
//    tile-t loads landed in LDS; barrier#1 => all waves landed. reads follow.
//  * buffer overwrite: stage at iter t writes buf[(t+2)%3], last read at
//    iter t-1; every wave's reads at t-1 completed before its barrier#2
//    (explicit lgkmcnt(0)), and stage at t is after barrier#2(t-1). safe.
template <int VM>
__device__ __forceinline__ void kstep(const u16* sAc, const u16* sBc,
                                      int fA, int fB, f32x4 (&acc)[4][4]) {
  asm volatile("s_waitcnt vmcnt(%0)" :: "n"(VM) : "memory");
  __builtin_amdgcn_s_barrier();              // barrier#1: tile resident
  __builtin_amdgcn_sched_barrier(0);
  bf16x8 af[4], bfr[4];
#pragma unroll
  for (int m = 0; m < 4; ++m) af[m]  = *(const bf16x8*)(sAc + fA + m * 512);
#pragma unroll
  for (int n = 0; n < 4; ++n) bfr[n] = *(const bf16x8*)(sBc + fB + n * 512);
  asm volatile("s_waitcnt lgkmcnt(0)" ::: "memory");
  __builtin_amdgcn_sched_barrier(0);         // rule #18: pin MFMA below wait
  __builtin_amdgcn_s_barrier();              // barrier#2: buffer reusable
  __builtin_amdgcn_sched_barrier(0);
  __builtin_amdgcn_s_setprio(1);
#pragma unroll
  for (int m = 0; m < 4; ++m)
#pragma unroll
    for (int n = 0; n < 4; ++n)
      acc[m][n] = __builtin_amdgcn_mfma_f32_16x16x32_bf16(af[m], bfr[n], acc[m][n], 0, 0, 0);
  __builtin_amdgcn_s_setprio(0);
}

__global__ __launch_bounds__(256, 3) void gemm_main(
    const u16* __restrict__ A, const u16* __restrict__ Wf,
    const float* __restrict__ beff, const float* __restrict__ resid,
    const int* __restrict__ mask, float* __restrict__ out) {
  __shared__ __align__(16) u16 sA[3][4096], sB[3][4096];  // 48 KB, 3 blocks/CU
  const int tid = threadIdx.x, wave = tid >> 6, lane = tid & 63;
  const int L = blockIdx.x;                 // 0..2047
  const int by = (L & 7) * 32 + (L >> 6);   // XCD L%8 owns 32 consecutive M-tiles
  const int bx = (L >> 3) & 7;              // 8 consecutive L share one A-panel
  const int task = mask[by >> 4];
  const u16* Bt = Wf + (size_t)task * (D_HID * D_HID);
  const int srow = tid >> 2, scol = (tid & 3) * 8;
  size_t aOff = (size_t)(by * 128 + srow) * D_HID + scol;
  size_t bOff = (size_t)(bx * 128 + srow) * D_HID + scol;
  const int wb = wave * 512;
  const int wm = wave >> 1, wn = wave & 1;
  const int mrow = lane & 15, quad = lane >> 4;
  const int fA = (wm * 64 + mrow) * 32 + quad * 8;
  const int fB = (wn * 64 + mrow) * 32 + quad * 8;
  f32x4 acc[4][4];
#pragma unroll
  for (int i = 0; i < 4; ++i)
#pragma unroll
    for (int j = 0; j < 4; ++j) acc[i][j] = (f32x4){0.f, 0.f, 0.f, 0.f};

  auto stage = [&](int buf) {
    gld16(A + aOff,               &sA[buf][wb]);
    gld16(A + aOff + 64 * D_HID,  &sA[buf][wb + 2048]);
    gld16(Bt + bOff,              &sB[buf][wb]);
    gld16(Bt + bOff + 64 * D_HID, &sB[buf][wb + 2048]);
    aOff += 32; bOff += 32;
  };

  stage(0);
  stage(1);
  int cur = 0;
  for (int t = 0; t < 30; ++t) {            // 32 K-steps total; last 2 peeled
    int sb = cur + 2; if (sb >= 3) sb -= 3;
    stage(sb);
    kstep<8>(&sA[cur][0], &sB[cur][0], fA, fB, acc);  // 8 newer loads in flight
    if (++cur == 3) cur = 0;
  }
  kstep<4>(&sA[cur][0], &sB[cur][0], fA, fB, acc);
  if (++cur == 3) cur = 0;
  kstep<0>(&sA[cur][0], &sB[cur][0], fA, fB, acc);

  // epilogue: + beff[task] + resid, fp32 store. C/D: col=lane&15, row=quad*4+r.
  const float* bb = beff + task * D_HID;
  const size_t mBase = (size_t)by * 128 + wm * 64;
  const int nBase = bx * 128 + wn * 64;
#pragma unroll
  for (int mf = 0; mf < 4; ++mf)
#pragma unroll
    for (int nf = 0; nf < 4; ++nf) {
      const int n = nBase + nf * 16 + mrow;
      const float bval = bb[n];
#pragma unroll
      for (int r = 0; r < 4; ++r) {
        const size_t m = mBase + mf * 16 + quad * 4 + r;
        out[m * D_HID + n] = acc[mf][nf][r] + bval + resid[m * D_HID + n];
      }
    }
}

// ---- in-place LN, one wave per row (no LDS, no sync) ----
__global__ __launch_bounds__(256) void ln4(float* __restrict__ io,
                                           const float* __restrict__ gamma,
                                           const float* __restrict__ beta) {
  const int row = blockIdx.x * 4 + (threadIdx.x >> 6);
  const int lane = threadIdx.x & 63;
  float* p = io + (size_t)row * D_HID + lane * 16;
  float4 v0 = ((const float4*)p)[0], v1 = ((const float4*)p)[1];
  float4 v2 = ((const float4*)p)[2], v3 = ((const float4*)p)[3];
  float s = v0.x + v0.y + v0.z + v0.w + v1.x + v1.y + v1.z + v1.w
          + v2.x + v2.y + v2.z + v2.w + v3.x + v3.y + v3.z + v3.w;
  float q = v0.x*v0.x + v0.y*v0.y + v0.z*v0.z + v0.w*v0.w
          + v1.x*v1.x + v1.y*v1.y + v1.z*v1.z + v1.w*v1.w
          + v2.x*v2.x + v2.y*v2.y + v2.z*v2.z + v2.w*v2.w
          + v3.x*v3.x + v3.y*v3.y + v3.z*v3.z + v3.w*v3.w;
#pragma unroll
  for (int m = 1; m < 64; m <<= 1) { s += __shfl_xor(s, m); q += __shfl_xor(q, m); }
  const float mu  = s * (1.f / (float)D_HID);
  const float var = q * (1.f / (float)D_HID) - mu * mu;
  const float inv = rsqrtf(var + LN_EPS);
  const float4* gp = (const float4*)(gamma + lane * 16);
  const float4* bp = (const float4*)(beta + lane * 16);
  float4 g, bbv, o;
#define LNW(k, vk) \
  g = gp[k]; bbv = bp[k]; \
  o.x = (vk.x - mu) * inv * g.x + bbv.x; o.y = (vk.y - mu) * inv * g.y + bbv.y; \
  o.z = (vk.z - mu) * inv * g.z + bbv.z; o.w = (vk.w - mu) * inv * g.w + bbv.w; \
  ((float4*)p)[k] = o;
  LNW(0, v0) LNW(1, v1) LNW(2, v2) LNW(3, v3)
#undef LNW
}

extern "C" void kernel_launch(void* const* d_in, const int* in_sizes, int n_in,
                              void* d_out, int out_size, void* d_ws, size_t ws_size,
                              hipStream_t stream) {
  const float* hs    = (const float*)d_in[0];  // [16,2048,1024] fp32
  const float* inp   = (const float*)d_in[1];  // [16,2048,1024] fp32
  const float* W     = (const float*)d_in[2];  // [1024,1024] fp32
  const float* b     = (const float*)d_in[3];  // [1024]
  const float* lA    = (const float*)d_in[4];  // [5,4,1024]
  const float* lB    = (const float*)d_in[5];  // [5,1024,4]
  const float* gamma = (const float*)d_in[6];
  const float* beta  = (const float*)d_in[7];
  const int*   mask  = (const int*)d_in[8];    // [16]
  float* out = (float*)d_out;

  // Workspace (81.9 MiB, unchanged footprint):
  //  [0,64M)      hs_bf bf16
  //  [64M,+4M)    Wc fp32
  //  [+4M,+10M)   Weff bf16 [5][1024][1024]. During S1/S2 its first 8 MB hold
  //               Whi/Wlo/WhiT/WloT and the next 512 KB hold lApad hi/lo
  //               (all dead before S3 writes Weff; stream-ordered).
  //  tail         A2 (80K), beff (20K)
  char* wsb = (char*)d_ws;
  u16*   hs_bf = (u16*)wsb;
  float* Wc    = (float*)(wsb + 67108864);
  u16*   weff  = (u16*)(wsb + 71303168);
  u16*   Whi   = weff;
  u16*   Wlo   = weff + 1048576;
  u16*   WhiT  = weff + 2097152;
  u16*   WloT  = weff + 3145728;
  u16*   lAh   = weff + 4194304;              // 128x1024 u16 = 256 KB
  u16*   lAl   = weff + 4325376;              // 256 KB (ends at 8.5 MB < 10 MB)
  float* A2    = (float*)(wsb + 81788928);
  float* beff  = (float*)(wsb + 81871360);

  s1_prep<<<3080, 256, 0, stream>>>(hs, hs_bf, W, Whi, Wlo, WhiT, WloT, lA, lAh, lAl);
  s2_gemm<<<72, 256, 0, stream>>>(Whi, Wlo, WhiT, WloT, lAh, lAl, Wc, A2);
  weff_beff<<<dim3(1024, 5), 256, 0, stream>>>(Wc, A2, lB, lA, W, b, weff, beff);
  gemm_main<<<2048, 256, 0, stream>>>(hs_bf, weff, beff, inp, mask, out);
  ln4<<<M_TOT / 4, 256, 0, stream>>>(out, gamma, beta);
}

// Round 4
// 548.331 us; speedup vs baseline: 1.0153x; 1.0153x over previous
//
#include <hip/hip_runtime.h>
#include <hip/hip_bf16.h>
#include <stdint.h>

// JinaEmbeddingsV3SelfOutput, algebraically folded:
//   h2 = hs @ Weff_t^T + beff_t,   Weff_t = W@W + 0.25*B_t@(A_t@W)  [per task]
//   beff_t = W@b + b + 0.25*B_t@(A_t@b)
//   out = LN(h2 + input)
// R4: gemm_main rebuilt as the 256x256 8-phase schedule (guide m201 template):
//     BK=64, 8 waves (2Mx4N), 128 KB LDS dbuf, 4 phases per K-tile, one
//     stage-half per phase, counted vmcnt(4) once per K-tile, XOR bank
//     swizzle (pre-swizzled global src + swizzled ds_read), setprio around
//     each 16-MFMA cluster.
#define D_HID 1024
#define M_TOT 32768
#define LN_EPS 1e-5f

typedef __bf16 bf16x8 __attribute__((ext_vector_type(8)));
typedef float f32x4 __attribute__((ext_vector_type(4)));
typedef unsigned short u16;
typedef u16 u16x8 __attribute__((ext_vector_type(8)));
typedef u16 u16x4v __attribute__((ext_vector_type(4)));

__device__ __forceinline__ float bf2f(u16 x) {
  union { unsigned int u; float f; } c; c.u = ((unsigned int)x) << 16; return c.f;
}
__device__ __forceinline__ u16 f2bf(float f) {
  union { __bf16 h; u16 u; } c; c.h = (__bf16)f; return c.u;  // RNE
}
__device__ __forceinline__ u16x8 cvt8(const float* g) {
  float4 f0 = *(const float4*)g;
  float4 f1 = *(const float4*)(g + 4);
  u16x8 v;
  v[0] = f2bf(f0.x); v[1] = f2bf(f0.y); v[2] = f2bf(f0.z); v[3] = f2bf(f0.w);
  v[4] = f2bf(f1.x); v[5] = f2bf(f1.y); v[6] = f2bf(f1.z); v[7] = f2bf(f1.w);
  return v;
}
// Async global->LDS, 16B/lane. LDS dest is wave-uniform base + lane*16.
__device__ __forceinline__ void gld16(const u16* g, u16* lds_wave_base) {
  __builtin_amdgcn_global_load_lds(
      (__attribute__((address_space(1))) unsigned int*)g,
      (__attribute__((address_space(3))) unsigned int*)lds_wave_base, 16, 0, 0);
}

// ---- S1: hs->bf16 (blocks 0..2047), W split+transpose (2048..3071),
//          lA zero-padded split (3072..3079) ----
__global__ __launch_bounds__(256) void s1_prep(
    const float* __restrict__ hs, u16* __restrict__ hs_bf,
    const float* __restrict__ W, u16* __restrict__ hi, u16* __restrict__ lo,
    u16* __restrict__ hiT, u16* __restrict__ loT,
    const float* __restrict__ lA, u16* __restrict__ lAh, u16* __restrict__ lAl) {
  __shared__ float tile[32][33];
  const int bid = blockIdx.x, tid = threadIdx.x;
  if (bid < 2048) {
    int i = bid * 256 + tid;
#pragma unroll
    for (int it = 0; it < 8; ++it, i += 2048 * 256)
      *(u16x8*)(hs_bf + (size_t)i * 8) = cvt8(hs + (size_t)i * 8);
    return;
  }
  if (bid >= 3072) {                  // lA pad+split: 128x1024, rows >=20 zero
    const int b = bid - 3072;
    for (int i = tid; i < 16 * 1024; i += 256) {
      const int r = b * 16 + (i >> 10), c = i & 1023;
      const float v = (r < 20) ? lA[(size_t)r * 1024 + c] : 0.f;
      const u16 h = f2bf(v);
      lAh[(size_t)r * 1024 + c] = h;
      lAl[(size_t)r * 1024 + c] = f2bf(v - bf2f(h));
    }
    return;
  }
  const int rb = bid - 2048;
  const int bj = rb & 31, bi = rb >> 5;
  const int tx = tid & 31, ty = tid >> 5;
#pragma unroll
  for (int r0 = 0; r0 < 32; r0 += 8) {
    const int r = r0 + ty;
    const size_t o = (size_t)(bi * 32 + r) * D_HID + bj * 32 + tx;
    const float v = W[o];
    tile[r][tx] = v;
    const u16 h = f2bf(v);
    hi[o] = h; lo[o] = f2bf(v - bf2f(h));
  }
  __syncthreads();
#pragma unroll
  for (int r0 = 0; r0 < 32; r0 += 8) {
    const int r = r0 + ty;
    const float v = tile[tx][r];
    const size_t o = (size_t)(bj * 32 + r) * D_HID + bi * 32 + tx;
    const u16 h = f2bf(v);
    hiT[o] = h; loT[o] = f2bf(v - bf2f(h));
  }
}

// ---- S2: [W; lApad] @ W via split-bf16 MFMA. by<8 -> Wc tile; by==8 -> A2 ----
__global__ __launch_bounds__(256, 1) void s2_gemm(
    const u16* __restrict__ Ah, const u16* __restrict__ Al,
    const u16* __restrict__ Bh, const u16* __restrict__ Bl,
    const u16* __restrict__ lAh, const u16* __restrict__ lAl,
    float* __restrict__ C, float* __restrict__ A2) {
  __shared__ __align__(16) u16 sAh[128 * 32], sAl[128 * 32];
  __shared__ __align__(16) u16 sBh[128 * 32], sBl[128 * 32];
  const int bid = blockIdx.x, tid = threadIdx.x, wave = tid >> 6, lane = tid & 63;
  const int by = bid >> 3, bx = bid & 7;
  const bool isA2 = (by == 8);
  const u16* Asrc_h = isA2 ? lAh : Ah;
  const u16* Asrc_l = isA2 ? lAl : Al;
  const int rowbase = isA2 ? 0 : by * 128;
  const int srow = tid >> 2, scol = (tid & 3) * 8;
  size_t aOff = (size_t)(rowbase + srow) * D_HID + scol;
  size_t bOff = (size_t)(bx * 128 + srow) * D_HID + scol;
  const int wb = wave * 512;
  const int wm = wave >> 1, wn = wave & 1;
  const int mrow = lane & 15, quad = lane >> 4;
  const int fA = (wm * 64 + mrow) * 32 + quad * 8;
  const int fB = (wn * 64 + mrow) * 32 + quad * 8;
  f32x4 acc[4][4];
#pragma unroll
  for (int i = 0; i < 4; ++i)
#pragma unroll
    for (int jn = 0; jn < 4; ++jn) acc[i][jn] = (f32x4){0.f, 0.f, 0.f, 0.f};
  for (int k0 = 0; k0 < D_HID; k0 += 32) {
    __syncthreads();
    gld16(Asrc_h + aOff, sAh + wb); gld16(Asrc_h + aOff + 64 * D_HID, sAh + wb + 2048);
    gld16(Asrc_l + aOff, sAl + wb); gld16(Asrc_l + aOff + 64 * D_HID, sAl + wb + 2048);
    gld16(Bh + bOff, sBh + wb); gld16(Bh + bOff + 64 * D_HID, sBh + wb + 2048);
    gld16(Bl + bOff, sBl + wb); gld16(Bl + bOff + 64 * D_HID, sBl + wb + 2048);
    aOff += 32; bOff += 32;
    __syncthreads();
    bf16x8 ah[4], al4[4], bh[4], bl4[4];
#pragma unroll
    for (int m = 0; m < 4; ++m) {
      ah[m]  = *(const bf16x8*)(sAh + fA + m * 512);
      al4[m] = *(const bf16x8*)(sAl + fA + m * 512);
    }
#pragma unroll
    for (int n = 0; n < 4; ++n) {
      bh[n]  = *(const bf16x8*)(sBh + fB + n * 512);
      bl4[n] = *(const bf16x8*)(sBl + fB + n * 512);
    }
#pragma unroll
    for (int m = 0; m < 4; ++m)
#pragma unroll
      for (int n = 0; n < 4; ++n) {
        acc[m][n] = __builtin_amdgcn_mfma_f32_16x16x32_bf16(ah[m],  bh[n],  acc[m][n], 0, 0, 0);
        acc[m][n] = __builtin_amdgcn_mfma_f32_16x16x32_bf16(al4[m], bh[n],  acc[m][n], 0, 0, 0);
        acc[m][n] = __builtin_amdgcn_mfma_f32_16x16x32_bf16(ah[m],  bl4[n], acc[m][n], 0, 0, 0);
      }
  }
  const int nBase = bx * 128 + wn * 64;
#pragma unroll
  for (int m = 0; m < 4; ++m)
#pragma unroll
    for (int n = 0; n < 4; ++n) {
      const int nn = nBase + n * 16 + mrow;
#pragma unroll
      for (int r = 0; r < 4; ++r) {
        const int lr = wm * 64 + m * 16 + quad * 4 + r;
        if (!isA2) {
          C[(size_t)(by * 128 + lr) * D_HID + nn] = acc[m][n][r];
        } else if (lr < 20) {
          A2[(size_t)lr * D_HID + nn] = acc[m][n][r];
        }
      }
    }
}

// ---- S3: Weff_t = bf16(Wc + 0.25*B_t@A2_t); beff_t (cvec dots inline) ----
__global__ __launch_bounds__(256) void weff_beff(
    const float* __restrict__ Wc, const float* __restrict__ A2,
    const float* __restrict__ lB, const float* __restrict__ lA,
    const float* __restrict__ W, const float* __restrict__ bvec,
    u16* __restrict__ Weff, float* __restrict__ beff) {
  const int n = blockIdx.x, t = blockIdx.y, tid = threadIdx.x;
  const int wave = tid >> 6, lane = tid & 63;
  float br[4];
#pragma unroll
  for (int r = 0; r < 4; ++r) br[r] = lB[(size_t)t * 4096 + n * 4 + r];
  float4 v = *(const float4*)(Wc + (size_t)n * D_HID + tid * 4);
#pragma unroll
  for (int r = 0; r < 4; ++r) {
    const float4 a2 = *(const float4*)(A2 + (size_t)(t * 4 + r) * D_HID + tid * 4);
    const float s = 0.25f * br[r];
    v.x += s * a2.x; v.y += s * a2.y; v.z += s * a2.z; v.w += s * a2.w;
  }
  u16x4v o; o[0] = f2bf(v.x); o[1] = f2bf(v.y); o[2] = f2bf(v.z); o[3] = f2bf(v.w);
  *(u16x4v*)(Weff + (size_t)t * 1048576 + (size_t)n * D_HID + tid * 4) = o;
  // beff[t][n] = W[n,:]·b + b[n] + 0.25 * sum_r B_t[n,r] * (lA[t,r,:]·b)
  const float4 bb = *(const float4*)(bvec + tid * 4);
  float p[5];
  {
    const float4 wr = *(const float4*)(W + (size_t)n * D_HID + tid * 4);
    p[0] = wr.x * bb.x + wr.y * bb.y + wr.z * bb.z + wr.w * bb.w;
  }
#pragma unroll
  for (int r = 0; r < 4; ++r) {
    const float4 ar = *(const float4*)(lA + (size_t)(t * 4 + r) * D_HID + tid * 4);
    p[1 + r] = ar.x * bb.x + ar.y * bb.y + ar.z * bb.z + ar.w * bb.w;
  }
#pragma unroll
  for (int m = 1; m < 64; m <<= 1)
#pragma unroll
    for (int jj = 0; jj < 5; ++jj) p[jj] += __shfl_xor(p[jj], m);
  __shared__ float red[4][5];
  if (lane == 0)
#pragma unroll
    for (int jj = 0; jj < 5; ++jj) red[wave][jj] = p[jj];
  __syncthreads();
  if (tid == 0) {
    float P = 0.f, Cr[4] = {0.f, 0.f, 0.f, 0.f};
#pragma unroll
    for (int w = 0; w < 4; ++w) {
      P += red[w][0];
#pragma unroll
      for (int r = 0; r < 4; ++r) Cr[r] += red[w][1 + r];
    }
    const float e = br[0]*Cr[0] + br[1]*Cr[1] + br[2]*Cr[2] + br[3]*Cr[3];
    beff[t * D_HID + n] = P + bvec[n] + 0.25f * e;
  }
}

// ---- main GEMM: out = hs_bf @ Weff[task]^T + beff + resid ----
// 256x256 tile, BK=64, 8 waves (2Mx4N; wave owns 128x64), 128 KB LDS dbuf.
// 4 phases/K-tile; each phase stages ONE matrix-half (2 gld16) and runs 16
// MFMA. LDS tile [256 r][64 k] bf16; octet slot s of row r holds logical
// octet s^(r&7) (pre-swizzled global src + same XOR on ds_read: quad's 16
// lanes spread over 8 slots -> 2-way bank alias = free).
// Hazards: A-half of a buf is read in ph0+ph2 -> free for staging from ph3;
// B-half read in ph0+ph1 -> free from ph2. Stage pattern per iter kt (c=kt&1):
// ph0:B1(kt+1), ph1:A1(kt+1), ph2:B0(kt+2->c), ph3:A0(kt+2->c). Every stage
// sits >=1 exit-barrier after the last read of its destination region.
// Data-ready: vmcnt(4) at ph3 (after its stage) leaves only kt+2's 2 halves
// in flight -> all of kt+1 landed; ph3's exit barrier makes it global before
// ph0(kt+1)'s ds_reads. Tail: vmcnt(0) at kt==14; no wait at kt==15.
__global__ __launch_bounds__(512, 1) void gemm_main(
    const u16* __restrict__ Ag, const u16* __restrict__ Wf,
    const float* __restrict__ beff, const float* __restrict__ resid,
    const int* __restrict__ mask, float* __restrict__ out) {
  __shared__ __align__(16) u16 sAf[2 * 16384];
  __shared__ __align__(16) u16 sBf[2 * 16384];
  const int tid = threadIdx.x, wave = tid >> 6, lane = tid & 63;
  const int L = blockIdx.x;                 // 512 blocks
  const int xcd = L & 7, j = L >> 3;
  const int bx = j & 3;                     // N-tile 0..3
  const int by = xcd * 16 + (j >> 2);       // M-tile 0..127; XCD-clustered
  const int task = mask[by >> 3];           // 256-row tile never crosses batch
  const u16* Bg = Wf + (size_t)task * (D_HID * D_HID);

  // staging: round q thread covers row half*128+q*64+wave*8+(lane>>3),
  // octet slot lane&7; global octet pre-swizzled by ^(row&7)=^(lane>>3).
  const int acol = ((lane & 7) ^ (lane >> 3)) * 8;
  const int aBase = (by * 256 + wave * 8 + (lane >> 3)) * D_HID + acol;
  const int bBase = (bx * 256 + wave * 8 + (lane >> 3)) * D_HID + acol;

  auto stageA = [&](int ktar, int half) {
#pragma unroll
    for (int q = 0; q < 2; ++q)
      gld16(Ag + (aBase + ktar * 64 + half * 131072 + q * 65536),
            sAf + ((ktar & 1) * 16384 + half * 8192 + q * 4096 + wave * 512));
  };
  auto stageB = [&](int ktar, int half) {
#pragma unroll
    for (int q = 0; q < 2; ++q)
      gld16(Bg + (bBase + ktar * 64 + half * 131072 + q * 65536),
            sBf + ((ktar & 1) * 16384 + half * 8192 + q * 4096 + wave * 512));
  };

  // fragment addressing (u16 units): row*64 + (octet^(row&7))*8; kk: ^32.
  const int wm = wave >> 2, wn = wave & 3;
  const int l15 = lane & 15, quad = lane >> 4, l7 = lane & 7;
  const int vA0 = (wm * 128 + l15) * 64 + ((quad ^ l7) * 8);
  const int vB0 = (wn * 64 + l15) * 64 + ((quad ^ l7) * 8);

  f32x4 acc[8][4];
#pragma unroll
  for (int i = 0; i < 8; ++i)
#pragma unroll
    for (int jn = 0; jn < 4; ++jn) acc[i][jn] = (f32x4){0.f, 0.f, 0.f, 0.f};

  // prologue: kt0 fully + B0/A0 of kt1 (B1/A1 of kt1 staged at ph0/ph1 of kt0)
  stageB(0, 0); stageB(0, 1); stageA(0, 0); stageA(0, 1);
  stageB(1, 0); stageA(1, 0);
  asm volatile("s_waitcnt vmcnt(4)" ::: "memory");  // kt0's 8 loads landed
  __builtin_amdgcn_s_barrier();
  __builtin_amdgcn_sched_barrier(0);

  bf16x8 a[4][2], b[4][2];
#pragma unroll 1
  for (int k2 = 0; k2 < 8; ++k2) {
#pragma unroll
    for (int par = 0; par < 2; ++par) {
      const int kt = k2 * 2 + par;
      const u16* pA = sAf + par * 16384;
      const u16* pB = sBf + par * 16384;
      const bool st01 = (par == 0) || (k2 < 7);  // kt < 15
      const bool st23 = (k2 < 7);                // kt < 14

      // -------- phase 0: (qm0, qn0) --------
#pragma unroll
      for (int m4 = 0; m4 < 4; ++m4) {
        a[m4][0] = *(const bf16x8*)(pA + (vA0 + m4 * 1024));
        a[m4][1] = *(const bf16x8*)(pA + ((vA0 ^ 32) + m4 * 1024));
      }
#pragma unroll
      for (int n2 = 0; n2 < 2; ++n2) {
        b[n2][0] = *(const bf16x8*)(pB + (vB0 + n2 * 1024));
        b[n2][1] = *(const bf16x8*)(pB + ((vB0 ^ 32) + n2 * 1024));
      }
      if (st01) stageB(kt + 1, 1);
      __builtin_amdgcn_s_barrier();
      asm volatile("s_waitcnt lgkmcnt(0)" ::: "memory");
      __builtin_amdgcn_sched_barrier(0);
      __builtin_amdgcn_s_setprio(1);
#pragma unroll
      for (int m4 = 0; m4 < 4; ++m4)
#pragma unroll
        for (int n2 = 0; n2 < 2; ++n2)
#pragma unroll
          for (int kk = 0; kk < 2; ++kk)
            acc[m4][n2] = __builtin_amdgcn_mfma_f32_16x16x32_bf16(
                a[m4][kk], b[n2][kk], acc[m4][n2], 0, 0, 0);
      __builtin_amdgcn_s_setprio(0);
      __builtin_amdgcn_s_barrier();
      __builtin_amdgcn_sched_barrier(0);

      // -------- phase 1: (qm0, qn1) --------
#pragma unroll
      for (int n2 = 0; n2 < 2; ++n2) {
        b[2 + n2][0] = *(const bf16x8*)(pB + (vB0 + (2 + n2) * 1024));
        b[2 + n2][1] = *(const bf16x8*)(pB + ((vB0 ^ 32) + (2 + n2) * 1024));
      }
      if (st01) stageA(kt + 1, 1);
      __builtin_amdgcn_s_barrier();
      asm volatile("s_waitcnt lgkmcnt(0)" ::: "memory");
      __builtin_amdgcn_sched_barrier(0);
      __builtin_amdgcn_s_setprio(1);
#pragma unroll
      for (int m4 = 0; m4 < 4; ++m4)
#pragma unroll
        for (int n2 = 0; n2 < 2; ++n2)
#pragma unroll
          for (int kk = 0; kk < 2; ++kk)
            acc[m4][2 + n2] = __builtin_amdgcn_mfma_f32_16x16x32_bf16(
                a[m4][kk], b[2 + n2][kk], acc[m4][2 + n2], 0, 0, 0);
      __builtin_amdgcn_s_setprio(0);
      __builtin_amdgcn_s_barrier();
      __builtin_amdgcn_sched_barrier(0);

      // -------- phase 2: (qm1, qn0) --------
#pragma unroll
      for (int m4 = 0; m4 < 4; ++m4) {
        a[m4][0] = *(const bf16x8*)(pA + (vA0 + (4 + m4) * 1024));
        a[m4][1] = *(const bf16x8*)(pA + ((vA0 ^ 32) + (4 + m4) * 1024));
      }
      if (st23) stageB(kt + 2, 0);
      __builtin_amdgcn_s_barrier();
      asm volatile("s_waitcnt lgkmcnt(0)" ::: "memory");
      __builtin_amdgcn_sched_barrier(0);
      __builtin_amdgcn_s_setprio(1);
#pragma unroll
      for (int m4 = 0; m4 < 4; ++m4)
#pragma unroll
        for (int n2 = 0; n2 < 2; ++n2)
#pragma unroll
          for (int kk = 0; kk < 2; ++kk)
            acc[4 + m4][n2] = __builtin_amdgcn_mfma_f32_16x16x32_bf16(
                a[m4][kk], b[n2][kk], acc[4 + m4][n2], 0, 0, 0);
      __builtin_amdgcn_s_setprio(0);
      __builtin_amdgcn_s_barrier();
      __builtin_amdgcn_sched_barrier(0);

      // -------- phase 3: (qm1, qn1) --------
      if (st23) stageA(kt + 2, 0);
      if (par == 0) {
        if (k2 < 7) { asm volatile("s_waitcnt vmcnt(4)" ::: "memory"); }
        else        { asm volatile("s_waitcnt vmcnt(0)" ::: "memory"); }
      } else {
        if (k2 < 7) { asm volatile("s_waitcnt vmcnt(4)" ::: "memory"); }
      }
      __builtin_amdgcn_s_barrier();
      asm volatile("s_waitcnt lgkmcnt(0)" ::: "memory");
      __builtin_amdgcn_sched_barrier(0);
      __builtin_amdgcn_s_setprio(1);
#pragma unroll
      for (int m4 = 0; m4 < 4; ++m4)
#pragma unroll
        for (int n2 = 0; n2 < 2; ++n2)
#pragma unroll
          for (int kk = 0; kk < 2; ++kk)
            acc[4 + m4][2 + n2] = __builtin_amdgcn_mfma_f32_16x16x32_bf16(
                a[m4][kk], b[2 + n2][kk], acc[4 + m4][2 + n2], 0, 0, 0);
      __builtin_amdgcn_s_setprio(0);
      __builtin_amdgcn_s_barrier();
      __builtin_amdgcn_sched_barrier(0);
    }
  }

  // epilogue: + beff[task] + resid, fp32 store. C/D: col=lane&15, row=quad*4+r.
  const float* bb = beff + task * D_HID;
  const size_t mBase = (size_t)by * 256 + wm * 128;
  const int nb0 = bx * 256 + wn * 64;
#pragma unroll
  for (int mf = 0; mf < 8; ++mf)
#pragma unroll
    for (int nf = 0; nf < 4; ++nf) {
      const int n = nb0 + nf * 16 + l15;
      const float bval = bb[n];
#pragma unroll
      for (int r = 0; r < 4; ++r) {
        const size_t m = mBase + mf * 16 + quad * 4 + r;
        out[m * D_HID + n] = acc[mf][nf][r] + bval + resid[m * D_HID + n];
      }
    }
}

// ---- in-place LN, one wave per row (no LDS, no sync) ----
__global__ __launch_bounds__(256) void ln4(float* __restrict__ io,
                                           const float* __restrict__ gamma,
                                           const float* __restrict__ beta) {
  const int row = blockIdx.x * 4 + (threadIdx.x >> 6);
  const int lane = threadIdx.x & 63;
  float* p = io + (size_t)row * D_HID + lane * 16;
  float4 v0 = ((const float4*)p)[0], v1 = ((const float4*)p)[1];
  float4 v2 = ((const float4*)p)[2], v3 = ((const float4*)p)[3];
  float s = v0.x + v0.y + v0.z + v0.w + v1.x + v1.y + v1.z + v1.w
          + v2.x + v2.y + v2.z + v2.w + v3.x + v3.y + v3.z + v3.w;
  float q = v0.x*v0.x + v0.y*v0.y + v0.z*v0.z + v0.w*v0.w
          + v1.x*v1.x + v1.y*v1.y + v1.z*v1.z + v1.w*v1.w
          + v2.x*v2.x + v2.y*v2.y + v2.z*v2.z + v2.w*v2.w
          + v3.x*v3.x + v3.y*v3.y + v3.z*v3.z + v3.w*v3.w;
#pragma unroll
  for (int m = 1; m < 64; m <<= 1) { s += __shfl_xor(s, m); q += __shfl_xor(q, m); }
  const float mu  = s * (1.f / (float)D_HID);
  const float var = q * (1.f / (float)D_HID) - mu * mu;
  const float inv = rsqrtf(var + LN_EPS);
  const float4* gp = (const float4*)(gamma + lane * 16);
  const float4* bp = (const float4*)(beta + lane * 16);
  float4 g, bbv, o;
#define LNW(k, vk) \
  g = gp[k]; bbv = bp[k]; \
  o.x = (vk.x - mu) * inv * g.x + bbv.x; o.y = (vk.y - mu) * inv * g.y + bbv.y; \
  o.z = (vk.z - mu) * inv * g.z + bbv.z; o.w = (vk.w - mu) * inv * g.w + bbv.w; \
  ((float4*)p)[k] = o;
  LNW(0, v0) LNW(1, v1) LNW(2, v2) LNW(3, v3)
#undef LNW
}

extern "C" void kernel_launch(void* const* d_in, const int* in_sizes, int n_in,
                              void* d_out, int out_size, void* d_ws, size_t ws_size,
                              hipStream_t stream) {
  const float* hs    = (const float*)d_in[0];  // [16,2048,1024] fp32
  const float* inp   = (const float*)d_in[1];  // [16,2048,1024] fp32
  const float* W     = (const float*)d_in[2];  // [1024,1024] fp32
  const float* b     = (const float*)d_in[3];  // [1024]
  const float* lA    = (const float*)d_in[4];  // [5,4,1024]
  const float* lB    = (const float*)d_in[5];  // [5,1024,4]
  const float* gamma = (const float*)d_in[6];
  const float* beta  = (const float*)d_in[7];
  const int*   mask  = (const int*)d_in[8];    // [16]
  float* out = (float*)d_out;

  // Workspace (81.9 MiB):
  //  [0,64M)      hs_bf bf16
  //  [64M,+4M)    Wc fp32
  //  [+4M,+10M)   Weff bf16 [5][1024][1024]; first 8.5 MB double as
  //               Whi/Wlo/WhiT/WloT + lApad hi/lo (dead before S3 writes).
  //  tail         A2 (80K), beff (20K)
  char* wsb = (char*)d_ws;
  u16*   hs_bf = (u16*)wsb;
  float* Wc    = (float*)(wsb + 67108864);
  u16*   weff  = (u16*)(wsb + 71303168);
  u16*   Whi   = weff;
  u16*   Wlo   = weff + 1048576;
  u16*   WhiT  = weff + 2097152;
  u16*   WloT  = weff + 3145728;
  u16*   lAh   = weff + 4194304;
  u16*   lAl   = weff + 4325376;
  float* A2    = (float*)(wsb + 81788928);
  float* beff  = (float*)(wsb + 81871360);

  s1_prep<<<3080, 256, 0, stream>>>(hs, hs_bf, W, Whi, Wlo, WhiT, WloT, lA, lAh, lAl);
  s2_gemm<<<72, 256, 0, stream>>>(Whi, Wlo, WhiT, WloT, lAh, lAl, Wc, A2);
  weff_beff<<<dim3(1024, 5), 256, 0, stream>>>(Wc, A2, lB, lA, W, b, weff, beff);
  gemm_main<<<512, 512, 0, stream>>>(hs_bf, weff, beff, inp, mask, out);
  ln4<<<M_TOT / 4, 256, 0, stream>>>(out, gamma, beta);
}

// Round 5
// 504.713 us; speedup vs baseline: 1.1031x; 1.0864x over previous
//
#include <hip/hip_runtime.h>
#include <hip/hip_bf16.h>
#include <stdint.h>

// JinaEmbeddingsV3SelfOutput, algebraically folded:
//   h2 = hs @ Weff_t^T + beff_t,   Weff_t = W@W + 0.25*B_t@(A_t@W)  [per task]
//   beff_t = W@b + b + 0.25*B_t@(A_t@b)
//   out = LN(h2 + input)
// R5: (1) resid-add moved from gemm_main epilogue into ln4 -> gemm epilogue is
//     store-only (no load-latency chain, no resid FETCH in gemm);
//     (2) s2 rebuilt at 64x64 tiles / 272 blocks (was 72 blocks @128x128 --
//     low-parallelism regression identified from R2->R3 totals);
//     (3) 8-phase gemm_main otherwise unchanged (one variable per region).
#define D_HID 1024
#define M_TOT 32768
#define LN_EPS 1e-5f

typedef __bf16 bf16x8 __attribute__((ext_vector_type(8)));
typedef float f32x4 __attribute__((ext_vector_type(4)));
typedef unsigned short u16;
typedef u16 u16x8 __attribute__((ext_vector_type(8)));
typedef u16 u16x4v __attribute__((ext_vector_type(4)));

__device__ __forceinline__ float bf2f(u16 x) {
  union { unsigned int u; float f; } c; c.u = ((unsigned int)x) << 16; return c.f;
}
__device__ __forceinline__ u16 f2bf(float f) {
  union { __bf16 h; u16 u; } c; c.h = (__bf16)f; return c.u;  // RNE
}
__device__ __forceinline__ u16x8 cvt8(const float* g) {
  float4 f0 = *(const float4*)g;
  float4 f1 = *(const float4*)(g + 4);
  u16x8 v;
  v[0] = f2bf(f0.x); v[1] = f2bf(f0.y); v[2] = f2bf(f0.z); v[3] = f2bf(f0.w);
  v[4] = f2bf(f1.x); v[5] = f2bf(f1.y); v[6] = f2bf(f1.z); v[7] = f2bf(f1.w);
  return v;
}
// Async global->LDS, 16B/lane. LDS dest is wave-uniform base + lane*16.
__device__ __forceinline__ void gld16(const u16* g, u16* lds_wave_base) {
  __builtin_amdgcn_global_load_lds(
      (__attribute__((address_space(1))) unsigned int*)g,
      (__attribute__((address_space(3))) unsigned int*)lds_wave_base, 16, 0, 0);
}

// ---- S1: hs->bf16 (blocks 0..2047), W split+transpose (2048..3071),
//          lA zero-padded split (3072..3079) ----
__global__ __launch_bounds__(256) void s1_prep(
    const float* __restrict__ hs, u16* __restrict__ hs_bf,
    const float* __restrict__ W, u16* __restrict__ hi, u16* __restrict__ lo,
    u16* __restrict__ hiT, u16* __restrict__ loT,
    const float* __restrict__ lA, u16* __restrict__ lAh, u16* __restrict__ lAl) {
  __shared__ float tile[32][33];
  const int bid = blockIdx.x, tid = threadIdx.x;
  if (bid < 2048) {
    int i = bid * 256 + tid;
#pragma unroll
    for (int it = 0; it < 8; ++it, i += 2048 * 256)
      *(u16x8*)(hs_bf + (size_t)i * 8) = cvt8(hs + (size_t)i * 8);
    return;
  }
  if (bid >= 3072) {                  // lA pad+split: 128x1024, rows >=20 zero
    const int b = bid - 3072;
    for (int i = tid; i < 16 * 1024; i += 256) {
      const int r = b * 16 + (i >> 10), c = i & 1023;
      const float v = (r < 20) ? lA[(size_t)r * 1024 + c] : 0.f;
      const u16 h = f2bf(v);
      lAh[(size_t)r * 1024 + c] = h;
      lAl[(size_t)r * 1024 + c] = f2bf(v - bf2f(h));
    }
    return;
  }
  const int rb = bid - 2048;
  const int bj = rb & 31, bi = rb >> 5;
  const int tx = tid & 31, ty = tid >> 5;
#pragma unroll
  for (int r0 = 0; r0 < 32; r0 += 8) {
    const int r = r0 + ty;
    const size_t o = (size_t)(bi * 32 + r) * D_HID + bj * 32 + tx;
    const float v = W[o];
    tile[r][tx] = v;
    const u16 h = f2bf(v);
    hi[o] = h; lo[o] = f2bf(v - bf2f(h));
  }
  __syncthreads();
#pragma unroll
  for (int r0 = 0; r0 < 32; r0 += 8) {
    const int r = r0 + ty;
    const float v = tile[tx][r];
    const size_t o = (size_t)(bj * 32 + r) * D_HID + bi * 32 + tx;
    const u16 h = f2bf(v);
    hiT[o] = h; loT[o] = f2bf(v - bf2f(h));
  }
}

// ---- S2: [W; lApad] @ W via split-bf16 MFMA, 64x64 tiles, 272 blocks.
//      by<16 -> Wc tile; by==16 -> A2 rows (first 20 kept). 4 waves; wave w
//      stages matrix w (Ah/Al/Bh/Bl, 4KB each) via 4 gld16; 16KB LDS. ----
__global__ __launch_bounds__(256) void s2_gemm(
    const u16* __restrict__ Ah, const u16* __restrict__ Al,
    const u16* __restrict__ Bh, const u16* __restrict__ Bl,
    const u16* __restrict__ lAh, const u16* __restrict__ lAl,
    float* __restrict__ C, float* __restrict__ A2) {
  __shared__ __align__(16) u16 smem[4][64 * 32];   // Ah,Al,Bh,Bl tiles
  const int bid = blockIdx.x, tid = threadIdx.x;
  const int wave = tid >> 6, lane = tid & 63;
  const int by = bid >> 4, bx = bid & 15;
  const bool isA2 = (by == 16);
  const u16* Asel_h = isA2 ? lAh : Ah;
  const u16* Asel_l = isA2 ? lAl : Al;
  const int arow0 = isA2 ? 0 : by * 64;
  const u16* gsel = (wave == 0) ? Asel_h : (wave == 1) ? Asel_l
                  : (wave == 2) ? Bh : Bl;
  const int rb = (wave < 2) ? arow0 : bx * 64;
  // gld16 chunk q covers rows q*16+(lane>>2), k-chunk (lane&3)*8;
  // LDS offset = q*512 + lane*8 (wave-uniform base + lane*16B).
  const u16* gp = gsel + (size_t)(rb + (lane >> 2)) * D_HID + (lane & 3) * 8;
  u16* sb = &smem[wave][0];

  const int l15 = lane & 15, quad = lane >> 4;
  const int wm = wave >> 1, wn = wave & 1;
  const int fA = (wm * 32 + l15) * 32 + quad * 8;
  const int fB = (wn * 32 + l15) * 32 + quad * 8;
  f32x4 acc[2][2];
#pragma unroll
  for (int m = 0; m < 2; ++m)
#pragma unroll
    for (int n = 0; n < 2; ++n) acc[m][n] = (f32x4){0.f, 0.f, 0.f, 0.f};

  for (int k0 = 0; k0 < D_HID; k0 += 32) {
    __syncthreads();
#pragma unroll
    for (int q = 0; q < 4; ++q)
      gld16(gp + (size_t)q * 16 * D_HID, sb + q * 512);
    gp += 32;
    __syncthreads();   // vmcnt(0) drain: tiles resident
    bf16x8 ahf[2], alf[2], bhf[2], blf[2];
#pragma unroll
    for (int m = 0; m < 2; ++m) {
      ahf[m] = *(const bf16x8*)(&smem[0][fA + m * 512]);
      alf[m] = *(const bf16x8*)(&smem[1][fA + m * 512]);
    }
#pragma unroll
    for (int n = 0; n < 2; ++n) {
      bhf[n] = *(const bf16x8*)(&smem[2][fB + n * 512]);
      blf[n] = *(const bf16x8*)(&smem[3][fB + n * 512]);
    }
#pragma unroll
    for (int m = 0; m < 2; ++m)
#pragma unroll
      for (int n = 0; n < 2; ++n) {
        acc[m][n] = __builtin_amdgcn_mfma_f32_16x16x32_bf16(ahf[m], bhf[n], acc[m][n], 0, 0, 0);
        acc[m][n] = __builtin_amdgcn_mfma_f32_16x16x32_bf16(alf[m], bhf[n], acc[m][n], 0, 0, 0);
        acc[m][n] = __builtin_amdgcn_mfma_f32_16x16x32_bf16(ahf[m], blf[n], acc[m][n], 0, 0, 0);
      }
  }
  const int nn0 = bx * 64 + wn * 32;
#pragma unroll
  for (int m = 0; m < 2; ++m)
#pragma unroll
    for (int n = 0; n < 2; ++n) {
      const int nn = nn0 + n * 16 + l15;
#pragma unroll
      for (int r = 0; r < 4; ++r) {
        const int lr = wm * 32 + m * 16 + quad * 4 + r;
        if (!isA2) {
          C[(size_t)(by * 64 + lr) * D_HID + nn] = acc[m][n][r];
        } else if (lr < 20) {
          A2[(size_t)lr * D_HID + nn] = acc[m][n][r];
        }
      }
    }
}

// ---- S3: Weff_t = bf16(Wc + 0.25*B_t@A2_t); beff_t (cvec dots inline) ----
__global__ __launch_bounds__(256) void weff_beff(
    const float* __restrict__ Wc, const float* __restrict__ A2,
    const float* __restrict__ lB, const float* __restrict__ lA,
    const float* __restrict__ W, const float* __restrict__ bvec,
    u16* __restrict__ Weff, float* __restrict__ beff) {
  const int n = blockIdx.x, t = blockIdx.y, tid = threadIdx.x;
  const int wave = tid >> 6, lane = tid & 63;
  float br[4];
#pragma unroll
  for (int r = 0; r < 4; ++r) br[r] = lB[(size_t)t * 4096 + n * 4 + r];
  float4 v = *(const float4*)(Wc + (size_t)n * D_HID + tid * 4);
#pragma unroll
  for (int r = 0; r < 4; ++r) {
    const float4 a2 = *(const float4*)(A2 + (size_t)(t * 4 + r) * D_HID + tid * 4);
    const float s = 0.25f * br[r];
    v.x += s * a2.x; v.y += s * a2.y; v.z += s * a2.z; v.w += s * a2.w;
  }
  u16x4v o; o[0] = f2bf(v.x); o[1] = f2bf(v.y); o[2] = f2bf(v.z); o[3] = f2bf(v.w);
  *(u16x4v*)(Weff + (size_t)t * 1048576 + (size_t)n * D_HID + tid * 4) = o;
  // beff[t][n] = W[n,:]·b + b[n] + 0.25 * sum_r B_t[n,r] * (lA[t,r,:]·b)
  const float4 bb = *(const float4*)(bvec + tid * 4);
  float p[5];
  {
    const float4 wr = *(const float4*)(W + (size_t)n * D_HID + tid * 4);
    p[0] = wr.x * bb.x + wr.y * bb.y + wr.z * bb.z + wr.w * bb.w;
  }
#pragma unroll
  for (int r = 0; r < 4; ++r) {
    const float4 ar = *(const float4*)(lA + (size_t)(t * 4 + r) * D_HID + tid * 4);
    p[1 + r] = ar.x * bb.x + ar.y * bb.y + ar.z * bb.z + ar.w * bb.w;
  }
#pragma unroll
  for (int m = 1; m < 64; m <<= 1)
#pragma unroll
    for (int jj = 0; jj < 5; ++jj) p[jj] += __shfl_xor(p[jj], m);
  __shared__ float red[4][5];
  if (lane == 0)
#pragma unroll
    for (int jj = 0; jj < 5; ++jj) red[wave][jj] = p[jj];
  __syncthreads();
  if (tid == 0) {
    float P = 0.f, Cr[4] = {0.f, 0.f, 0.f, 0.f};
#pragma unroll
    for (int w = 0; w < 4; ++w) {
      P += red[w][0];
#pragma unroll
      for (int r = 0; r < 4; ++r) Cr[r] += red[w][1 + r];
    }
    const float e = br[0]*Cr[0] + br[1]*Cr[1] + br[2]*Cr[2] + br[3]*Cr[3];
    beff[t * D_HID + n] = P + bvec[n] + 0.25f * e;
  }
}

// ---- main GEMM: h2 = hs_bf @ Weff[task]^T + beff (STORE-ONLY epilogue;
//      resid-add deferred to ln4). 256x256 tile, BK=64, 8 waves, 128 KB dbuf,
//      8-phase counted-vmcnt schedule with XOR bank swizzle (R4, unchanged). ----
__global__ __launch_bounds__(512, 1) void gemm_main(
    const u16* __restrict__ Ag, const u16* __restrict__ Wf,
    const float* __restrict__ beff, const int* __restrict__ mask,
    float* __restrict__ out) {
  __shared__ __align__(16) u16 sAf[2 * 16384];
  __shared__ __align__(16) u16 sBf[2 * 16384];
  const int tid = threadIdx.x, wave = tid >> 6, lane = tid & 63;
  const int L = blockIdx.x;                 // 512 blocks
  const int xcd = L & 7, j = L >> 3;
  const int bx = j & 3;                     // N-tile 0..3
  const int by = xcd * 16 + (j >> 2);       // M-tile 0..127; XCD-clustered
  const int task = mask[by >> 3];           // 256-row tile never crosses batch
  const u16* Bg = Wf + (size_t)task * (D_HID * D_HID);

  const int acol = ((lane & 7) ^ (lane >> 3)) * 8;
  const int aBase = (by * 256 + wave * 8 + (lane >> 3)) * D_HID + acol;
  const int bBase = (bx * 256 + wave * 8 + (lane >> 3)) * D_HID + acol;

  auto stageA = [&](int ktar, int half) {
#pragma unroll
    for (int q = 0; q < 2; ++q)
      gld16(Ag + (aBase + ktar * 64 + half * 131072 + q * 65536),
            sAf + ((ktar & 1) * 16384 + half * 8192 + q * 4096 + wave * 512));
  };
  auto stageB = [&](int ktar, int half) {
#pragma unroll
    for (int q = 0; q < 2; ++q)
      gld16(Bg + (bBase + ktar * 64 + half * 131072 + q * 65536),
            sBf + ((ktar & 1) * 16384 + half * 8192 + q * 4096 + wave * 512));
  };

  const int wm = wave >> 2, wn = wave & 3;
  const int l15 = lane & 15, quad = lane >> 4, l7 = lane & 7;
  const int vA0 = (wm * 128 + l15) * 64 + ((quad ^ l7) * 8);
  const int vB0 = (wn * 64 + l15) * 64 + ((quad ^ l7) * 8);

  f32x4 acc[8][4];
#pragma unroll
  for (int i = 0; i < 8; ++i)
#pragma unroll
    for (int jn = 0; jn < 4; ++jn) acc[i][jn] = (f32x4){0.f, 0.f, 0.f, 0.f};

  stageB(0, 0); stageB(0, 1); stageA(0, 0); stageA(0, 1);
  stageB(1, 0); stageA(1, 0);
  asm volatile("s_waitcnt vmcnt(4)" ::: "memory");
  __builtin_amdgcn_s_barrier();
  __builtin_amdgcn_sched_barrier(0);

  bf16x8 a[4][2], b[4][2];
#pragma unroll 1
  for (int k2 = 0; k2 < 8; ++k2) {
#pragma unroll
    for (int par = 0; par < 2; ++par) {
      const int kt = k2 * 2 + par;
      const u16* pA = sAf + par * 16384;
      const u16* pB = sBf + par * 16384;
      const bool st01 = (par == 0) || (k2 < 7);  // kt < 15
      const bool st23 = (k2 < 7);                // kt < 14

      // -------- phase 0: (qm0, qn0) --------
#pragma unroll
      for (int m4 = 0; m4 < 4; ++m4) {
        a[m4][0] = *(const bf16x8*)(pA + (vA0 + m4 * 1024));
        a[m4][1] = *(const bf16x8*)(pA + ((vA0 ^ 32) + m4 * 1024));
      }
#pragma unroll
      for (int n2 = 0; n2 < 2; ++n2) {
        b[n2][0] = *(const bf16x8*)(pB + (vB0 + n2 * 1024));
        b[n2][1] = *(const bf16x8*)(pB + ((vB0 ^ 32) + n2 * 1024));
      }
      if (st01) stageB(kt + 1, 1);
      __builtin_amdgcn_s_barrier();
      asm volatile("s_waitcnt lgkmcnt(0)" ::: "memory");
      __builtin_amdgcn_sched_barrier(0);
      __builtin_amdgcn_s_setprio(1);
#pragma unroll
      for (int m4 = 0; m4 < 4; ++m4)
#pragma unroll
        for (int n2 = 0; n2 < 2; ++n2)
#pragma unroll
          for (int kk = 0; kk < 2; ++kk)
            acc[m4][n2] = __builtin_amdgcn_mfma_f32_16x16x32_bf16(
                a[m4][kk], b[n2][kk], acc[m4][n2], 0, 0, 0);
      __builtin_amdgcn_s_setprio(0);
      __builtin_amdgcn_s_barrier();
      __builtin_amdgcn_sched_barrier(0);

      // -------- phase 1: (qm0, qn1) --------
#pragma unroll
      for (int n2 = 0; n2 < 2; ++n2) {
        b[2 + n2][0] = *(const bf16x8*)(pB + (vB0 + (2 + n2) * 1024));
        b[2 + n2][1] = *(const bf16x8*)(pB + ((vB0 ^ 32) + (2 + n2) * 1024));
      }
      if (st01) stageA(kt + 1, 1);
      __builtin_amdgcn_s_barrier();
      asm volatile("s_waitcnt lgkmcnt(0)" ::: "memory");
      __builtin_amdgcn_sched_barrier(0);
      __builtin_amdgcn_s_setprio(1);
#pragma unroll
      for (int m4 = 0; m4 < 4; ++m4)
#pragma unroll
        for (int n2 = 0; n2 < 2; ++n2)
#pragma unroll
          for (int kk = 0; kk < 2; ++kk)
            acc[m4][2 + n2] = __builtin_amdgcn_mfma_f32_16x16x32_bf16(
                a[m4][kk], b[2 + n2][kk], acc[m4][2 + n2], 0, 0, 0);
      __builtin_amdgcn_s_setprio(0);
      __builtin_amdgcn_s_barrier();
      __builtin_amdgcn_sched_barrier(0);

      // -------- phase 2: (qm1, qn0) --------
#pragma unroll
      for (int m4 = 0; m4 < 4; ++m4) {
        a[m4][0] = *(const bf16x8*)(pA + (vA0 + (4 + m4) * 1024));
        a[m4][1] = *(const bf16x8*)(pA + ((vA0 ^ 32) + (4 + m4) * 1024));
      }
      if (st23) stageB(kt + 2, 0);
      __builtin_amdgcn_s_barrier();
      asm volatile("s_waitcnt lgkmcnt(0)" ::: "memory");
      __builtin_amdgcn_sched_barrier(0);
      __builtin_amdgcn_s_setprio(1);
#pragma unroll
      for (int m4 = 0; m4 < 4; ++m4)
#pragma unroll
        for (int n2 = 0; n2 < 2; ++n2)
#pragma unroll
          for (int kk = 0; kk < 2; ++kk)
            acc[4 + m4][n2] = __builtin_amdgcn_mfma_f32_16x16x32_bf16(
                a[m4][kk], b[n2][kk], acc[4 + m4][n2], 0, 0, 0);
      __builtin_amdgcn_s_setprio(0);
      __builtin_amdgcn_s_barrier();
      __builtin_amdgcn_sched_barrier(0);

      // -------- phase 3: (qm1, qn1) --------
      if (st23) stageA(kt + 2, 0);
      if (par == 0) {
        if (k2 < 7) { asm volatile("s_waitcnt vmcnt(4)" ::: "memory"); }
        else        { asm volatile("s_waitcnt vmcnt(0)" ::: "memory"); }
      } else {
        if (k2 < 7) { asm volatile("s_waitcnt vmcnt(4)" ::: "memory"); }
      }
      __builtin_amdgcn_s_barrier();
      asm volatile("s_waitcnt lgkmcnt(0)" ::: "memory");
      __builtin_amdgcn_sched_barrier(0);
      __builtin_amdgcn_s_setprio(1);
#pragma unroll
      for (int m4 = 0; m4 < 4; ++m4)
#pragma unroll
        for (int n2 = 0; n2 < 2; ++n2)
#pragma unroll
          for (int kk = 0; kk < 2; ++kk)
            acc[4 + m4][2 + n2] = __builtin_amdgcn_mfma_f32_16x16x32_bf16(
                a[m4][kk], b[2 + n2][kk], acc[4 + m4][2 + n2], 0, 0, 0);
      __builtin_amdgcn_s_setprio(0);
      __builtin_amdgcn_s_barrier();
      __builtin_amdgcn_sched_barrier(0);
    }
  }

  // store-only epilogue: h2 = acc + beff. C/D: col=lane&15, row=quad*4+r.
  const float* bb = beff + task * D_HID;
  const size_t mBase = (size_t)by * 256 + wm * 128;
  const int nb0 = bx * 256 + wn * 64;
#pragma unroll
  for (int mf = 0; mf < 8; ++mf)
#pragma unroll
    for (int nf = 0; nf < 4; ++nf) {
      const int n = nb0 + nf * 16 + l15;
      const float bval = bb[n];
#pragma unroll
      for (int r = 0; r < 4; ++r) {
        const size_t m = mBase + mf * 16 + quad * 4 + r;
        out[m * D_HID + n] = acc[mf][nf][r] + bval;
      }
    }
}

// ---- ln4: out = LN(h2 + resid), in-place on io(h2); one wave per row ----
__global__ __launch_bounds__(256) void ln4(float* __restrict__ io,
                                           const float* __restrict__ resid,
                                           const float* __restrict__ gamma,
                                           const float* __restrict__ beta) {
  const int row = blockIdx.x * 4 + (threadIdx.x >> 6);
  const int lane = threadIdx.x & 63;
  float* p = io + (size_t)row * D_HID + lane * 16;
  const float* rp = resid + (size_t)row * D_HID + lane * 16;
  float4 v0 = ((const float4*)p)[0], v1 = ((const float4*)p)[1];
  float4 v2 = ((const float4*)p)[2], v3 = ((const float4*)p)[3];
  float4 r0 = ((const float4*)rp)[0], r1 = ((const float4*)rp)[1];
  float4 r2 = ((const float4*)rp)[2], r3 = ((const float4*)rp)[3];
  v0.x += r0.x; v0.y += r0.y; v0.z += r0.z; v0.w += r0.w;
  v1.x += r1.x; v1.y += r1.y; v1.z += r1.z; v1.w += r1.w;
  v2.x += r2.x; v2.y += r2.y; v2.z += r2.z; v2.w += r2.w;
  v3.x += r3.x; v3.y += r3.y; v3.z += r3.z; v3.w += r3.w;
  float s = v0.x + v0.y + v0.z + v0.w + v1.x + v1.y + v1.z + v1.w
          + v2.x + v2.y + v2.z + v2.w + v3.x + v3.y + v3.z + v3.w;
  float q = v0.x*v0.x + v0.y*v0.y + v0.z*v0.z + v0.w*v0.w
          + v1.x*v1.x + v1.y*v1.y + v1.z*v1.z + v1.w*v1.w
          + v2.x*v2.x + v2.y*v2.y + v2.z*v2.z + v2.w*v2.w
          + v3.x*v3.x + v3.y*v3.y + v3.z*v3.z + v3.w*v3.w;
#pragma unroll
  for (int m = 1; m < 64; m <<= 1) { s += __shfl_xor(s, m); q += __shfl_xor(q, m); }
  const float mu  = s * (1.f / (float)D_HID);
  const float var = q * (1.f / (float)D_HID) - mu * mu;
  const float inv = rsqrtf(var + LN_EPS);
  const float4* gp = (const float4*)(gamma + lane * 16);
  const float4* bp = (const float4*)(beta + lane * 16);
  float4 g, bbv, o;
#define LNW(k, vk) \
  g = gp[k]; bbv = bp[k]; \
  o.x = (vk.x - mu) * inv * g.x + bbv.x; o.y = (vk.y - mu) * inv * g.y + bbv.y; \
  o.z = (vk.z - mu) * inv * g.z + bbv.z; o.w = (vk.w - mu) * inv * g.w + bbv.w; \
  ((float4*)p)[k] = o;
  LNW(0, v0) LNW(1, v1) LNW(2, v2) LNW(3, v3)
#undef LNW
}

extern "C" void kernel_launch(void* const* d_in, const int* in_sizes, int n_in,
                              void* d_out, int out_size, void* d_ws, size_t ws_size,
                              hipStream_t stream) {
  const float* hs    = (const float*)d_in[0];  // [16,2048,1024] fp32
  const float* inp   = (const float*)d_in[1];  // [16,2048,1024] fp32
  const float* W     = (const float*)d_in[2];  // [1024,1024] fp32
  const float* b     = (const float*)d_in[3];  // [1024]
  const float* lA    = (const float*)d_in[4];  // [5,4,1024]
  const float* lB    = (const float*)d_in[5];  // [5,1024,4]
  const float* gamma = (const float*)d_in[6];
  const float* beta  = (const float*)d_in[7];
  const int*   mask  = (const int*)d_in[8];    // [16]
  float* out = (float*)d_out;

  // Workspace (81.9 MiB):
  //  [0,64M)      hs_bf bf16
  //  [64M,+4M)    Wc fp32
  //  [+4M,+10M)   Weff bf16 [5][1024][1024]; first 8.5 MB double as
  //               Whi/Wlo/WhiT/WloT + lApad hi/lo (dead before S3 writes).
  //  tail         A2 (80K), beff (20K)
  char* wsb = (char*)d_ws;
  u16*   hs_bf = (u16*)wsb;
  float* Wc    = (float*)(wsb + 67108864);
  u16*   weff  = (u16*)(wsb + 71303168);
  u16*   Whi   = weff;
  u16*   Wlo   = weff + 1048576;
  u16*   WhiT  = weff + 2097152;
  u16*   WloT  = weff + 3145728;
  u16*   lAh   = weff + 4194304;
  u16*   lAl   = weff + 4325376;
  float* A2    = (float*)(wsb + 81788928);
  float* beff  = (float*)(wsb + 81871360);

  s1_prep<<<3080, 256, 0, stream>>>(hs, hs_bf, W, Whi, Wlo, WhiT, WloT, lA, lAh, lAl);
  s2_gemm<<<272, 256, 0, stream>>>(Whi, Wlo, WhiT, WloT, lAh, lAl, Wc, A2);
  weff_beff<<<dim3(1024, 5), 256, 0, stream>>>(Wc, A2, lB, lA, W, b, weff, beff);
  gemm_main<<<512, 512, 0, stream>>>(hs_bf, weff, beff, mask, out);
  ln4<<<M_TOT / 4, 256, 0, stream>>>(out, inp, gamma, beta);
}